// Round 1
// baseline (472.961 us; speedup 1.0000x reference)
//
#include <hip/hip_runtime.h>
#include <cstdint>
#include <cstddef>

#define B_    16
#define C_    256
#define HW_   64
#define N_    4096      // 64*64 spatial
#define K_    512
#define NROW_ 65536     // B_*N_

struct P2 { float v1; int k1; float v2; int k2; };

__device__ __forceinline__ bool lexless(float v, int k, float bv, int bk) {
    return (v < bv) || (v == bv && k < bk);
}
__device__ __forceinline__ void ins2(float v, int k, float& v1, int& k1, float& v2, int& k2) {
    if (lexless(v, k, v1, k1)) { v2 = v1; k2 = k1; v1 = v; k1 = k; }
    else if (lexless(v, k, v2, k2)) { v2 = v; k2 = k; }
}

// ---------------- kernel 1: codebook squared norms (+ zero loss accumulator) ----
__global__ void e2_kernel(const float* __restrict__ cb, float* __restrict__ e2,
                          double* __restrict__ lossAcc) {
    int k = blockIdx.x, t = threadIdx.x;
    if (k == 0 && t == 0) *lossAcc = 0.0;
    float4 v = *(const float4*)(cb + (size_t)k * C_ + t * 4);
    float s = v.x*v.x + v.y*v.y + v.z*v.z + v.w*v.w;
    #pragma unroll
    for (int off = 32; off; off >>= 1) s += __shfl_down(s, off);
    if (t == 0) e2[k] = s;
}

// ---------------- kernel 2: query squared norms -------------------------------
// row id = b*4096 + w*64 + h0 ; X[row,c] = pq[b, c, h0*64 + w]
__global__ void x2_kernel(const float* __restrict__ pq, float* __restrict__ x2) {
    int h0 = blockIdx.x, b = blockIdx.y, w = threadIdx.x;
    const float* p = pq + (size_t)b * C_ * N_ + h0 * HW_ + w;
    float s = 0.f;
    #pragma unroll 4
    for (int c = 0; c < C_; ++c) { float v = p[(size_t)c * N_]; s = fmaf(v, v, s); }
    x2[b * N_ + w * HW_ + h0] = s;
}

// ---------------- kernel 3: GEMM + per-row top-2 argmin -----------------------
// grid (kchunk=4, h0=64, b=16); block 256. Tile: 64 rows (w=0..63) x 128 k.
// Per-thread: 4 rows x 8 k. v = e2[k] - 2*x.e  (x2 added later; constant per row).
__launch_bounds__(256)
__global__ void main_kernel(const float* __restrict__ pq, const float* __restrict__ cb,
                            const float* __restrict__ e2, P2* __restrict__ partials) {
    const int kchunk = blockIdx.x, h0 = blockIdx.y, b = blockIdx.z;
    const int tid = threadIdx.x;
    const int kx = tid & 15, rx = tid >> 4;
    const int k0 = kchunk * 128;

    __shared__ float Xs[16][64];      // [c][w]
    __shared__ float Es[16 * 132];    // [c] x {j-half(64) | kx*4 | j&3}, pad stride 132

    const float* pqb = pq + (size_t)b * (C_ * N_) + h0 * HW_;

    float acc[4][8];
    #pragma unroll
    for (int i = 0; i < 4; ++i)
        #pragma unroll
        for (int j = 0; j < 8; ++j) acc[i][j] = 0.f;

    // staging maps (fixed per thread)
    const int s_cl  = tid >> 4;            // 0..15  (c within tile) for Xs
    const int s_w4  = (tid & 15) << 2;     // 0..60  (w, float4)
    const int s_kl  = tid >> 1;            // 0..127 (k within chunk) for Es
    const int s_q   = tid & 1;             // which 8-float half of the 16-c slab
    const int s_kxg = s_kl >> 3, s_j = s_kl & 7;
    const int s_ebase = ((s_j >> 2) << 6) + (s_kxg << 2) + (s_j & 3);
    const float* cbrow = cb + (size_t)(k0 + s_kl) * C_ + s_q * 8;

    for (int tile = 0; tile < 16; ++tile) {
        const int c0 = tile << 4;
        __syncthreads();
        // stage X tile (coalesced 256B segments along w)
        float4 xv = *(const float4*)(pqb + (size_t)(c0 + s_cl) * N_ + s_w4);
        *(float4*)&Xs[s_cl][s_w4] = xv;
        // stage E tile transposed (codebook rows are contiguous reads)
        float4 A  = *(const float4*)(cbrow + c0);
        float4 Bv = *(const float4*)(cbrow + c0 + 4);
        float ev[8] = {A.x, A.y, A.z, A.w, Bv.x, Bv.y, Bv.z, Bv.w};
        #pragma unroll
        for (int m = 0; m < 8; ++m)
            Es[(s_q * 8 + m) * 132 + s_ebase] = ev[m];
        __syncthreads();

        #pragma unroll
        for (int c = 0; c < 16; ++c) {
            float4 a  = *(const float4*)&Xs[c][rx << 2];            // broadcast x16 lanes
            const float* ep = &Es[c * 132 + (kx << 2)];
            float4 b0 = *(const float4*)ep;                          // j = 0..3
            float4 b1 = *(const float4*)(ep + 64);                   // j = 4..7
            float av[4] = {a.x, a.y, a.z, a.w};
            float bv[8] = {b0.x, b0.y, b0.z, b0.w, b1.x, b1.y, b1.z, b1.w};
            #pragma unroll
            for (int i = 0; i < 4; ++i)
                #pragma unroll
                for (int j = 0; j < 8; ++j)
                    acc[i][j] = fmaf(av[i], bv[j], acc[i][j]);
        }
    }

    // epilogue: per-thread per-row top-2 over its 8 k's
    float e2v[8];
    #pragma unroll
    for (int j = 0; j < 8; ++j) e2v[j] = e2[k0 + kx * 8 + j];

    float v1[4], v2[4]; int k1[4], k2[4];
    #pragma unroll
    for (int i = 0; i < 4; ++i) {
        v1[i] = v2[i] = __builtin_inff(); k1[i] = k2[i] = 0x7fffffff;
        #pragma unroll
        for (int j = 0; j < 8; ++j) {
            float v = fmaf(-2.f, acc[i][j], e2v[j]);
            ins2(v, k0 + kx * 8 + j, v1[i], k1[i], v2[i], k2[i]);
        }
    }
    // butterfly top-2 merge across the 16 lanes sharing this row-set
    #pragma unroll
    for (int m = 1; m < 16; m <<= 1) {
        #pragma unroll
        for (int i = 0; i < 4; ++i) {
            float ov1 = __shfl_xor(v1[i], m); int ok1 = __shfl_xor(k1[i], m);
            float ov2 = __shfl_xor(v2[i], m); int ok2 = __shfl_xor(k2[i], m);
            ins2(ov1, ok1, v1[i], k1[i], v2[i], k2[i]);
            ins2(ov2, ok2, v1[i], k1[i], v2[i], k2[i]);
        }
    }
    if (kx == 0) {
        #pragma unroll
        for (int i = 0; i < 4; ++i) {
            int w = (rx << 2) + i;
            size_t row = (size_t)b * N_ + w * HW_ + h0;
            P2 p; p.v1 = v1[i]; p.k1 = k1[i]; p.v2 = v2[i]; p.k2 = k2[i];
            partials[(size_t)kchunk * NROW_ + row] = p;
        }
    }
}

// ---------------- kernel 4: merge chunks, fp64 refine near-ties, loss --------
#define MARGIN 0.05f
__global__ void merge_kernel(const P2* __restrict__ partials, const float* __restrict__ x2,
                             const float* __restrict__ pq, const float* __restrict__ cb,
                             int* __restrict__ idx, double* __restrict__ lossAcc) {
    int row = blockIdx.x * 256 + threadIdx.x;
    float v1 = __builtin_inff(), v2 = __builtin_inff();
    int k1 = 0x7fffffff, k2 = 0x7fffffff;
    #pragma unroll
    for (int c = 0; c < 4; ++c) {
        P2 p = partials[(size_t)c * NROW_ + row];
        ins2(p.v1, p.k1, v1, k1, v2, k2);
        ins2(p.v2, p.k2, v1, k1, v2, k2);
    }
    int b = row >> 12, n = row & 4095, w = n >> 6, h = n & 63;
    int kwin = k1;
    double d2min;
    if (v2 - v1 < MARGIN) {
        // exact fp64 re-evaluation of both candidates (rare path)
        const float* xp  = pq + (size_t)b * (C_ * N_) + h * HW_ + w;
        const float* ca  = cb + (size_t)k1 * C_;
        const float* cbp = cb + (size_t)k2 * C_;
        double da = 0.0, db = 0.0;
        for (int c = 0; c < C_; ++c) {
            double xv = (double)xp[(size_t)c * N_];
            double ea = xv - (double)ca[c];  da += ea * ea;
            double eb = xv - (double)cbp[c]; db += eb * eb;
        }
        if (db < da || (db == da && k2 < k1)) { kwin = k2; d2min = db; }
        else d2min = da;
    } else {
        d2min = (double)(x2[row] + v1);
    }
    idx[row] = kwin;
    // block-reduce loss partial, one f64 atomic per block
    double s = d2min;
    #pragma unroll
    for (int off = 32; off; off >>= 1) s += __shfl_down(s, off);
    __shared__ double ls[4];
    if ((threadIdx.x & 63) == 0) ls[threadIdx.x >> 6] = s;
    __syncthreads();
    if (threadIdx.x == 0) atomicAdd(lossAcc, ls[0] + ls[1] + ls[2] + ls[3]);
}

// ---------------- kernel 5: gather codebook rows -> output (+ loss finalize) --
__global__ void scatter_kernel(const float* __restrict__ cb, const int* __restrict__ idx,
                               const double* __restrict__ lossAcc, float* __restrict__ out) {
    int ntile = blockIdx.x, b = blockIdx.y, tid = threadIdx.x;
    __shared__ int idxs[64];
    __shared__ float tile[64][65];
    if (tid < 64) idxs[tid] = idx[b * N_ + ntile * 64 + tid];
    if (b == 0 && ntile == 0 && tid == 0)
        out[(size_t)B_ * C_ * N_] =
            (float)(1.25 * (*lossAcc) / (double)((size_t)B_ * N_ * C_));
    __syncthreads();
    for (int cc = 0; cc < 4; ++cc) {
        int c0 = cc * 64;
        #pragma unroll
        for (int p = 0; p < 16; ++p) {
            int i = p * 4 + (tid >> 6);
            int c = tid & 63;
            tile[i][c] = cb[(size_t)idxs[i] * C_ + c0 + c];   // coalesced 256B rows
        }
        __syncthreads();
        #pragma unroll
        for (int p = 0; p < 16; ++p) {
            int cl = p * 4 + (tid >> 6);
            int nl = tid & 63;
            out[((size_t)(b * C_ + c0 + cl)) * N_ + ntile * 64 + nl] = tile[nl][cl];
        }
        __syncthreads();
    }
}

// ---------------- launch ------------------------------------------------------
extern "C" void kernel_launch(void* const* d_in, const int* in_sizes, int n_in,
                              void* d_out, int out_size, void* d_ws, size_t ws_size,
                              hipStream_t stream) {
    const float* pq = (const float*)d_in[0];   // [16,256,64,64]
    const float* cb = (const float*)d_in[1];   // [512,256]
    float* out = (float*)d_out;                // 4194304 out + 1 loss
    char* ws = (char*)d_ws;
    // ws layout: [0,8) lossAcc | [16,2064) e2 | [2064,+256K) x2 | (+256K) idx | (+) partials 4MB
    double* lossAcc = (double*)ws;
    float* e2 = (float*)(ws + 16);
    float* x2 = (float*)(ws + 16 + 2048);
    int*   idx = (int*)(ws + 16 + 2048 + 262144);
    P2* partials = (P2*)(ws + 16 + 2048 + 262144 + 262144);

    e2_kernel<<<K_, 64, 0, stream>>>(cb, e2, lossAcc);
    x2_kernel<<<dim3(HW_, B_), 64, 0, stream>>>(pq, x2);
    main_kernel<<<dim3(4, HW_, B_), 256, 0, stream>>>(pq, cb, e2, partials);
    merge_kernel<<<NROW_ / 256, 256, 0, stream>>>(partials, x2, pq, cb, idx, lossAcc);
    scatter_kernel<<<dim3(HW_, B_), 256, 0, stream>>>(cb, idx, lossAcc, out);
}